// Round 10
// baseline (2403.327 us; speedup 1.0000x reference)
//
#include <hip/hip_runtime.h>
#include <hip/hip_bf16.h>
#include <math.h>

// Shapes: B=16, C=256, H=W=96, S=3, OUT_C=64
#define NPOS 9216
#define PERB 2359296ull        // 256*9216 elements (one [C][H*W] plane-set)

typedef unsigned short u16;
typedef __attribute__((ext_vector_type(8))) short short8;  // bf16x8 MFMA frag
typedef __attribute__((ext_vector_type(4))) float f32x4;   // MFMA acc

__device__ inline u16 bfhi(float x) {
    unsigned int b = __float_as_uint(x);
    return (u16)((b + 0x7FFFu + ((b >> 16) & 1u)) >> 16);   // RNE f32->bf16
}
__device__ inline float bf2f(u16 u) { return __uint_as_float(((unsigned int)u) << 16); }

// ---------------------------------------------------------------------------
// Separable positional-encoding table: T[c][p], c=4j+r.
// pe[c][h*96+w] == T[c][w] + T[c][h];  r0: sin(p/95*f), r1: cos, r2/3: 0.
// ---------------------------------------------------------------------------
__global__ __launch_bounds__(256) void tt_kernel(float* __restrict__ T)
{
    int idx = blockIdx.x * 256 + threadIdx.x;   // 0..24575 (256c x 96p)
    int c = idx / 96, p = idx - (idx / 96) * 96;
    int j = c >> 2, r = c & 3;
    float f = expf(-(float)(2 * j) * 0.07195578415f);  // ln(10000)/128
    float x = (float)p * (1.0f / 95.0f) * f;
    T[idx] = (r == 0) ? sinf(x) : (r == 1) ? cosf(x) : 0.0f;
}

// ---------------------------------------------------------------------------
// Weight split: W[s][mat][256][256] f32 -> blocked bf16 hi/lo (plain layout)
// layout: [s][mat*2+mb][kb][128 rows][32 k]   (k-contiguous rows)
// ---------------------------------------------------------------------------
__global__ __launch_bounds__(256) void wsplit(
    const float* __restrict__ qw, const float* __restrict__ kw,
    const float* __restrict__ vw, u16* __restrict__ whi, u16* __restrict__ wlo)
{
    int bid = blockIdx.x;
    int s = bid / 48, rem = bid % 48;
    int mat = rem / 16, rem2 = rem % 16;
    int mb = rem2 / 8, kb = rem2 % 8;
    const float* W = ((mat == 0) ? qw : (mat == 1) ? kw : vw) + (size_t)s * 65536;
    int t = threadIdx.x;
    int m = t >> 1, kh = (t & 1) * 16;
    const float* src = W + (size_t)(mb * 128 + m) * 256 + kb * 32 + kh;
    size_t ob = (size_t)s * 196608 + (size_t)((mat * 2 + mb) * 8 + kb) * 4096
              + (size_t)m * 32 + kh;
    u16 hv[16], lv[16];
#pragma unroll
    for (int j = 0; j < 16; ++j) {
        float x = src[j];
        u16 h = bfhi(x);
        hv[j] = h;
        lv[j] = bfhi(x - bf2f(h));
    }
    *(uint4*)(whi + ob)     = *(uint4*)hv;
    *(uint4*)(whi + ob + 8) = *(uint4*)(hv + 8);
    *(uint4*)(wlo + ob)     = *(uint4*)lv;
    *(uint4*)(wlo + ob + 8) = *(uint4*)(lv + 8);
}

// ---------------------------------------------------------------------------
// Input split+transpose: src[b][256][9216] f32 -> blocked bf16 hi/lo (plain)
// layout per batch: [tau=nb*8+kb][128 n][32 k]
// ---------------------------------------------------------------------------
__global__ __launch_bounds__(256) void splitcvt(
    const float* __restrict__ src, u16* __restrict__ hi, u16* __restrict__ lo)
{
    __shared__ float ls[32 * 132];
    int tau = blockIdx.x;          // 0..575
    int nb = tau >> 3, kb = tau & 7;
    int b = blockIdx.y;
    const float* in = src + (size_t)b * PERB + (size_t)(kb * 32) * NPOS + nb * 128;
    int t = threadIdx.x;
#pragma unroll
    for (int i = 0; i < 4; ++i) {
        int idx = i * 256 + t;
        int r = idx >> 5, nq = (idx & 31) * 4;
        *(float4*)&ls[r * 132 + nq] = *(const float4*)&in[(size_t)r * NPOS + nq];
    }
    __syncthreads();
    int n = t >> 1, kh = (t & 1) * 16;
    size_t ob = (size_t)b * PERB + (size_t)tau * 4096 + (size_t)n * 32 + kh;
    u16 hv[16], lv[16];
#pragma unroll
    for (int j = 0; j < 16; ++j) {
        float x = ls[(kh + j) * 132 + n];
        u16 h = bfhi(x);
        hv[j] = h;
        lv[j] = bfhi(x - bf2f(h));
    }
    *(uint4*)(hi + ob)     = *(uint4*)hv;
    *(uint4*)(hi + ob + 8) = *(uint4*)(hv + 8);
    *(uint4*)(lo + ob)     = *(uint4*)lv;
    *(uint4*)(lo + ob + 8) = *(uint4*)(lv + 8);
}

// ---------------------------------------------------------------------------
// MFMA QKV GEMM, split-bf16 — BARRIER-FREE: no LDS; every wave reads its A/B
// fragments directly from global (wave's 64 lanes cover a contiguous 1KB
// block -> perfectly coalesced; A is L1/L2-resident, B is L2-hot via XCD
// swizzle).  Waves free-run; TLP hides L2 latency.
// ---------------------------------------------------------------------------
__global__ __launch_bounds__(256, 3) void gemm_qkv_mfma(
    const u16* __restrict__ whi, const u16* __restrict__ wlo,
    const u16* __restrict__ b1hi, const u16* __restrict__ b1lo,
    const u16* __restrict__ b2hi, const u16* __restrict__ b2lo,
    const float* __restrict__ qb, const float* __restrict__ kbias,
    const float* __restrict__ vb, const float* __restrict__ wvis,
    const float* __restrict__ wir, const float* __restrict__ Ttab,
    float* __restrict__ qo, float* __restrict__ ko, float* __restrict__ vo)
{
    int t = threadIdx.x;
    // bijective XCD-chunk swizzle: 432 = 54*8; consecutive roles share an XCD
    int d = blockIdx.x + 6 * blockIdx.y;           // 0..431 (dispatch order)
    int role = (d & 7) * 54 + (d >> 3);
    int mat = role / 144, rem = role - mat * 144;
    int bn = rem >> 1, mtile = rem & 1;            // mtile pair adjacent roles
    int b = blockIdx.z;

    const u16* gBh = ((mat == 0) ? b1hi : b2hi) + (size_t)b * PERB + (size_t)bn * 32768;
    const u16* gBl = ((mat == 0) ? b1lo : b2lo) + (size_t)b * PERB + (size_t)bn * 32768;
    const u16* gAh = whi + (size_t)(mat * 2 + mtile) * 32768;
    const u16* gAl = wlo + (size_t)(mat * 2 + mtile) * 32768;
    int wm = t >> 7, wn = (t >> 6) & 1;
    int rr = t & 15, gq = (t >> 4) & 3;

    // per-lane fragment offsets (u16 units) within a [128][32] k-block
    int offA = (wm * 64 + rr) * 32 + gq * 8;
    int offB = (wn * 64 + rr) * 32 + gq * 8;
    const u16* pAh = gAh + offA;
    const u16* pAl = gAl + offA;
    const u16* pBh = gBh + offB;
    const u16* pBl = gBl + offB;

    f32x4 acc[4][4];
#pragma unroll
    for (int i = 0; i < 4; ++i)
#pragma unroll
        for (int j = 0; j < 4; ++j) acc[i][j] = (f32x4){0.f, 0.f, 0.f, 0.f};

#pragma unroll
    for (int kq = 0; kq < 8; ++kq) {
        short8 ah[4], al[4], bh[4], bl[4];
#pragma unroll
        for (int f = 0; f < 4; ++f) {
            ah[f] = *(const short8*)(pAh + kq * 4096 + f * 512);
            al[f] = *(const short8*)(pAl + kq * 4096 + f * 512);
        }
#pragma unroll
        for (int r = 0; r < 4; ++r) {
            bh[r] = *(const short8*)(pBh + kq * 4096 + r * 512);
            bl[r] = *(const short8*)(pBl + kq * 4096 + r * 512);
        }
#pragma unroll
        for (int f = 0; f < 4; ++f)
#pragma unroll
            for (int r = 0; r < 4; ++r) {
                acc[f][r] = __builtin_amdgcn_mfma_f32_16x16x32_bf16(ah[f], bh[r], acc[f][r], 0, 0, 0);
                acc[f][r] = __builtin_amdgcn_mfma_f32_16x16x32_bf16(ah[f], bl[r], acc[f][r], 0, 0, 0);
                acc[f][r] = __builtin_amdgcn_mfma_f32_16x16x32_bf16(al[f], bh[r], acc[f][r], 0, 0, 0);
            }
    }

    // epilogue: scale + bias (+ separable pe via L2-resident table)
    const float* wmap = ((mat == 0) ? wvis : wir) + (size_t)b * NPOS;
    const float* bias = (mat == 0) ? qb : (mat == 1) ? kbias : vb;
    float* outp = ((mat == 0) ? qo : (mat == 1) ? ko : vo) + (size_t)b * PERB;
    bool addpe = (mat != 2);
#pragma unroll
    for (int r = 0; r < 4; ++r) {
        int n = bn * 128 + wn * 64 + r * 16 + rr;
        float sc = wmap[n];
        int hh = n / 96, ww = n - hh * 96;
#pragma unroll
        for (int f = 0; f < 4; ++f)
#pragma unroll
            for (int ri = 0; ri < 4; ++ri) {
                int o = mtile * 128 + wm * 64 + f * 16 + gq * 4 + ri;
                float vvv = acc[f][r][ri] * sc + bias[o];
                if (addpe) vvv += Ttab[o * 96 + ww] + Ttab[o * 96 + hh];
                outp[(size_t)o * NPOS + n] = vvv;
            }
    }
}

// ---------------------------------------------------------------------------
// Attention per (b,c): 2-buffer LDS (77KB -> 2 blocks/CU).
// R1 = q then attn; R2 = k then v.  Contiguous f32 output (coalesced).
// ---------------------------------------------------------------------------
__global__ __launch_bounds__(256) void attn_kernel(
    const float* __restrict__ q, const float* __restrict__ k,
    const float* __restrict__ v, float* __restrict__ fused)
{
    __shared__ float R1[96 * 100];  // q, later attn
    __shared__ float R2[96 * 100];  // k, later v

    int t  = threadIdx.x;
    int bc = blockIdx.x;
    const size_t base = (size_t)bc * NPOS;

    for (int f = t; f < 96 * 24; f += 256) {
        int r = f / 24, w4 = (f % 24) * 4;
        *(float4*)(R1 + r * 100 + w4) = *(const float4*)(q + base + r * 96 + w4);
        *(float4*)(R2 + r * 100 + w4) = *(const float4*)(k + base + r * 96 + w4);
    }
    __syncthreads();

    int tx = t & 15, ty = t >> 4;
    int h0 = ty * 6, g0 = tx * 6;

    float acc[6][6];
#pragma unroll
    for (int i = 0; i < 6; ++i)
#pragma unroll
        for (int j = 0; j < 6; ++j) acc[i][j] = 0.0f;

    for (int w4 = 0; w4 < 24; ++w4) {
        float4 qv[6], kv[6];
#pragma unroll
        for (int i = 0; i < 6; ++i) qv[i] = *(const float4*)(R1 + (h0 + i) * 100 + w4 * 4);
#pragma unroll
        for (int j = 0; j < 6; ++j) kv[j] = *(const float4*)(R2 + (g0 + j) * 100 + w4 * 4);
#pragma unroll
        for (int i = 0; i < 6; ++i)
#pragma unroll
            for (int j = 0; j < 6; ++j) {
                acc[i][j] = fmaf(qv[i].x, kv[j].x, acc[i][j]);
                acc[i][j] = fmaf(qv[i].y, kv[j].y, acc[i][j]);
                acc[i][j] = fmaf(qv[i].z, kv[j].z, acc[i][j]);
                acc[i][j] = fmaf(qv[i].w, kv[j].w, acc[i][j]);
            }
    }

#pragma unroll
    for (int i = 0; i < 6; ++i) {
        float m = acc[i][0];
#pragma unroll
        for (int j = 1; j < 6; ++j) m = fmaxf(m, acc[i][j]);
        for (int d = 1; d < 16; d <<= 1) m = fmaxf(m, __shfl_xor(m, d));
        float s = 0.0f;
#pragma unroll
        for (int j = 0; j < 6; ++j) {
            acc[i][j] = __expf(acc[i][j] - m);
            s += acc[i][j];
        }
        for (int d = 1; d < 16; d <<= 1) s += __shfl_xor(s, d);
        float inv = 1.0f / s;
#pragma unroll
        for (int j = 0; j < 6; ++j) acc[i][j] *= inv;
    }

    __syncthreads();
#pragma unroll
    for (int i = 0; i < 6; ++i)
#pragma unroll
        for (int j = 0; j < 6; ++j) R1[(h0 + i) * 100 + g0 + j] = acc[i][j];
    for (int f = t; f < 96 * 24; f += 256) {
        int r = f / 24, w4 = (f % 24) * 4;
        *(float4*)(R2 + r * 100 + w4) = *(const float4*)(v + base + r * 96 + w4);
    }
    __syncthreads();

    int w0 = tx * 6;
    float outv[6][6];
#pragma unroll
    for (int i = 0; i < 6; ++i)
#pragma unroll
        for (int j = 0; j < 6; ++j) outv[i][j] = 0.0f;

    for (int g4 = 0; g4 < 24; ++g4) {
        float4 av[6];
#pragma unroll
        for (int i = 0; i < 6; ++i) av[i] = *(const float4*)(R1 + (h0 + i) * 100 + g4 * 4);
#pragma unroll
        for (int gg = 0; gg < 4; ++gg) {
            int g = g4 * 4 + gg;
            float vr[6];
#pragma unroll
            for (int j = 0; j < 6; ++j) vr[j] = R2[g * 100 + w0 + j];
#pragma unroll
            for (int i = 0; i < 6; ++i) {
                float a = (gg == 0) ? av[i].x : (gg == 1) ? av[i].y : (gg == 2) ? av[i].z : av[i].w;
#pragma unroll
                for (int j = 0; j < 6; ++j) outv[i][j] = fmaf(a, vr[j], outv[i][j]);
            }
        }
    }

#pragma unroll
    for (int i = 0; i < 6; ++i) {
        float* op = fused + base + (size_t)(h0 + i) * 96 + w0;
#pragma unroll
        for (int j = 0; j < 6; ++j) op[j] = outv[i][j];
    }
}

// ---------------------------------------------------------------------------
// Final projection: out[b][o][n] = sum_c proj_w[o][c]*fused[b][c][n] + pb[o]
// ---------------------------------------------------------------------------
__global__ __launch_bounds__(256) void proj_kernel(
    const float* __restrict__ fused, const float* __restrict__ pw,
    const float* __restrict__ pb, float* __restrict__ out)
{
    __shared__ float As[16 * 68];
    __shared__ float Bs[16 * 128];

    int t  = threadIdx.x;
    int n0 = blockIdx.x * 128;
    int b  = blockIdx.y;
    const float* B = fused + (size_t)b * PERB;
    int tx = t & 15, ty = t >> 4;

    float acc[4][8];
#pragma unroll
    for (int i = 0; i < 4; ++i)
#pragma unroll
        for (int j = 0; j < 8; ++j) acc[i][j] = 0.0f;

    for (int k0 = 0; k0 < 256; k0 += 16) {
        {
            int m = t >> 2, c4 = (t & 3) * 4;
            float4 av = *(const float4*)(pw + (size_t)m * 256 + k0 + c4);
            As[(c4 + 0) * 68 + m] = av.x;
            As[(c4 + 1) * 68 + m] = av.y;
            As[(c4 + 2) * 68 + m] = av.z;
            As[(c4 + 3) * 68 + m] = av.w;
        }
#pragma unroll
        for (int l = 0; l < 2; ++l) {
            int f = t + l * 256;
            int c = f >> 5, n4 = (f & 31) * 4;
            *(float4*)(Bs + c * 128 + n4) =
                *(const float4*)(B + (size_t)(k0 + c) * NPOS + n0 + n4);
        }
        __syncthreads();
#pragma unroll
        for (int kk = 0; kk < 16; ++kk) {
            float a[4], bb[8];
            *(float4*)(&a[0])  = *(const float4*)(As + kk * 68 + ty * 4);
            *(float4*)(&bb[0]) = *(const float4*)(Bs + kk * 128 + tx * 8);
            *(float4*)(&bb[4]) = *(const float4*)(Bs + kk * 128 + tx * 8 + 4);
#pragma unroll
            for (int i = 0; i < 4; ++i)
#pragma unroll
                for (int j = 0; j < 8; ++j)
                    acc[i][j] = fmaf(a[i], bb[j], acc[i][j]);
        }
        __syncthreads();
    }

    int n = n0 + tx * 8;
#pragma unroll
    for (int i = 0; i < 4; ++i) {
        int o = ty * 4 + i;
        float bias = pb[o];
        float vals[8];
#pragma unroll
        for (int j = 0; j < 8; ++j) vals[j] = acc[i][j] + bias;
        float* op = out + ((size_t)b * 64 + o) * NPOS + n;
        *(float4*)(op)     = *(float4*)(&vals[0]);
        *(float4*)(op + 4) = *(float4*)(&vals[4]);
    }
}

// ---------------------------------------------------------------------------
extern "C" void kernel_launch(void* const* d_in, const int* in_sizes, int n_in,
                              void* d_out, int out_size, void* d_ws, size_t ws_size,
                              hipStream_t stream)
{
    const float* x1   = (const float*)d_in[0];
    const float* x2   = (const float*)d_in[1];
    const float* wvis = (const float*)d_in[2];
    const float* wir  = (const float*)d_in[3];
    const float* qw   = (const float*)d_in[4];
    const float* qb   = (const float*)d_in[5];
    const float* kw   = (const float*)d_in[6];
    const float* kb   = (const float*)d_in[7];
    const float* vw   = (const float*)d_in[8];
    const float* vb   = (const float*)d_in[9];
    const float* pw   = (const float*)d_in[10];
    const float* pb   = (const float*)d_in[11];
    float* out = (float*)d_out;

    float* ws = (float*)d_ws;
    size_t F = ws_size / 4;
    size_t fixed = 700000;   // T table (24576) + weights (~590K f32-equiv)
    size_t avail = (F > fixed) ? (F - fixed) : 0;
    int G = (int)(avail / (6 * PERB));
    if (G < 1) G = 1;
    if (G > 8) G = 8;

    float* ttab  = ws;                       // 24576 floats
    float* qbuf  = ws + 24576;
    float* kbuf  = qbuf + (size_t)G * PERB;
    float* vbuf  = kbuf + (size_t)G * PERB;
    float* fbuf  = vbuf + (size_t)G * PERB;
    u16*   b1hi  = (u16*)(fbuf + (size_t)G * PERB);
    u16*   b1lo  = b1hi + (size_t)G * PERB;
    u16*   b2hi  = b1lo + (size_t)G * PERB;
    u16*   b2lo  = b2hi + (size_t)G * PERB;
    u16*   whiP  = b2lo + (size_t)G * PERB;
    u16*   wloP  = whiP + 589824;

    tt_kernel<<<dim3(96), 256, 0, stream>>>(ttab);
    wsplit<<<dim3(144), 256, 0, stream>>>(qw, kw, vw, whiP, wloP);

    for (int b0 = 0; b0 < 16; b0 += G) {
        int g = (16 - b0 < G) ? (16 - b0) : G;
        splitcvt<<<dim3(576, g), 256, 0, stream>>>(x1 + (size_t)b0 * PERB, b1hi, b1lo);
        splitcvt<<<dim3(576, g), 256, 0, stream>>>(x2 + (size_t)b0 * PERB, b2hi, b2lo);
        for (int s = 0; s < 3; ++s) {
            if (s > 0)
                splitcvt<<<dim3(576, g), 256, 0, stream>>>(fbuf, b1hi, b1lo);
            const u16* xh = (s == 0) ? b2hi : b1hi;
            const u16* xl = (s == 0) ? b2lo : b1lo;
            gemm_qkv_mfma<<<dim3(6, 72, g), 256, 0, stream>>>(
                whiP + (size_t)s * 196608, wloP + (size_t)s * 196608,
                b1hi, b1lo, xh, xl,
                qb + (size_t)s * 256, kb + (size_t)s * 256, vb + (size_t)s * 256,
                wvis + (size_t)b0 * NPOS, wir + (size_t)b0 * NPOS,
                ttab, qbuf, kbuf, vbuf);
            attn_kernel<<<dim3(256 * g), 256, 0, stream>>>(qbuf, kbuf, vbuf, fbuf);
        }
        proj_kernel<<<dim3(72, g), 256, 0, stream>>>(
            fbuf, pw, pb, out + (size_t)b0 * 64 * NPOS);
    }
}

// Round 11
// 2112.628 us; speedup vs baseline: 1.1376x; 1.1376x over previous
//
#include <hip/hip_runtime.h>
#include <hip/hip_bf16.h>
#include <math.h>

// Shapes: B=16, C=256, H=W=96, S=3, OUT_C=64
#define NPOS 9216
#define PERB 2359296ull        // 256*9216 elements (one [C][H*W] plane-set)

typedef unsigned short u16;
typedef __attribute__((ext_vector_type(8))) short short8;  // bf16x8 MFMA frag
typedef __attribute__((ext_vector_type(4))) float f32x4;   // MFMA acc

__device__ inline u16 bfhi(float x) {
    unsigned int b = __float_as_uint(x);
    return (u16)((b + 0x7FFFu + ((b >> 16) & 1u)) >> 16);   // RNE f32->bf16
}
__device__ inline float bf2f(u16 u) { return __uint_as_float(((unsigned int)u) << 16); }

// async global->LDS, 16B per lane (dest = uniform base + lane*16)
typedef const __attribute__((address_space(1))) void* gvp;
typedef __attribute__((address_space(3))) void* lvp;
__device__ __forceinline__ void glds16(const void* g, void* l) {
    __builtin_amdgcn_global_load_lds((gvp)g, (lvp)l, 16, 0, 0);
}

// ---------------------------------------------------------------------------
// Separable positional-encoding table: T[c][p], c=4j+r.
// pe[c][h*96+w] == T[c][w] + T[c][h];  r0: sin(p/95*f), r1: cos, r2/3: 0.
// ---------------------------------------------------------------------------
__global__ __launch_bounds__(256) void tt_kernel(float* __restrict__ T)
{
    int idx = blockIdx.x * 256 + threadIdx.x;   // 0..24575 (256c x 96p)
    int c = idx / 96, p = idx - (idx / 96) * 96;
    int j = c >> 2, r = c & 3;
    float f = expf(-(float)(2 * j) * 0.07195578415f);  // ln(10000)/128
    float x = (float)p * (1.0f / 95.0f) * f;
    T[idx] = (r == 0) ? sinf(x) : (r == 1) ? cosf(x) : 0.0f;
}

// ---------------------------------------------------------------------------
// Weight split: W[s][mat][256][256] f32 -> blocked bf16 hi/lo, XOR-swizzled.
// layout: [s][mat*2+mb][kb][128 rows][4 slots][8] with slot ^= (row>>1)&3
// ---------------------------------------------------------------------------
__global__ __launch_bounds__(256) void wsplit(
    const float* __restrict__ qw, const float* __restrict__ kw,
    const float* __restrict__ vw, u16* __restrict__ whi, u16* __restrict__ wlo)
{
    int bid = blockIdx.x;
    int s = bid / 48, rem = bid % 48;
    int mat = rem / 16, rem2 = rem % 16;
    int mb = rem2 / 8, kb = rem2 % 8;
    const float* W = ((mat == 0) ? qw : (mat == 1) ? kw : vw) + (size_t)s * 65536;
    int t = threadIdx.x;
    int m = t >> 1, kh = (t & 1) * 16;
    const float* src = W + (size_t)(mb * 128 + m) * 256 + kb * 32 + kh;
    int s0 = kh >> 3;                  // 0 or 2
    int sw = (m >> 1) & 3;
    size_t ob = (size_t)s * 196608 + (size_t)((mat * 2 + mb) * 8 + kb) * 4096
              + (size_t)m * 32;
    u16 hv[16], lv[16];
#pragma unroll
    for (int j = 0; j < 16; ++j) {
        float x = src[j];
        u16 h = bfhi(x);
        hv[j] = h;
        lv[j] = bfhi(x - bf2f(h));
    }
    *(uint4*)(whi + ob + ((s0 ^ sw) * 8))       = *(uint4*)hv;
    *(uint4*)(whi + ob + (((s0 + 1) ^ sw) * 8)) = *(uint4*)(hv + 8);
    *(uint4*)(wlo + ob + ((s0 ^ sw) * 8))       = *(uint4*)lv;
    *(uint4*)(wlo + ob + (((s0 + 1) ^ sw) * 8)) = *(uint4*)(lv + 8);
}

// ---------------------------------------------------------------------------
// Input split+transpose: src[b][256][9216] f32 -> blocked bf16 hi/lo, swizzled
// layout per batch: [tau=nb*8+kb][128 n][32 k], slot ^= (n>>1)&3
// ---------------------------------------------------------------------------
__global__ __launch_bounds__(256) void splitcvt(
    const float* __restrict__ src, u16* __restrict__ hi, u16* __restrict__ lo)
{
    __shared__ float ls[32 * 132];
    int tau = blockIdx.x;          // 0..575
    int nb = tau >> 3, kb = tau & 7;
    int b = blockIdx.y;
    const float* in = src + (size_t)b * PERB + (size_t)(kb * 32) * NPOS + nb * 128;
    int t = threadIdx.x;
#pragma unroll
    for (int i = 0; i < 4; ++i) {
        int idx = i * 256 + t;
        int r = idx >> 5, nq = (idx & 31) * 4;
        *(float4*)&ls[r * 132 + nq] = *(const float4*)&in[(size_t)r * NPOS + nq];
    }
    __syncthreads();
    int n = t >> 1, kh = (t & 1) * 16;
    int s0 = kh >> 3;
    int sw = (n >> 1) & 3;
    size_t ob = (size_t)b * PERB + (size_t)tau * 4096 + (size_t)n * 32;
    u16 hv[16], lv[16];
#pragma unroll
    for (int j = 0; j < 16; ++j) {
        float x = ls[(kh + j) * 132 + n];
        u16 h = bfhi(x);
        hv[j] = h;
        lv[j] = bfhi(x - bf2f(h));
    }
    *(uint4*)(hi + ob + ((s0 ^ sw) * 8))       = *(uint4*)hv;
    *(uint4*)(hi + ob + (((s0 + 1) ^ sw) * 8)) = *(uint4*)(hv + 8);
    *(uint4*)(lo + ob + ((s0 ^ sw) * 8))       = *(uint4*)lv;
    *(uint4*)(lo + ob + (((s0 + 1) ^ sw) * 8)) = *(uint4*)(lv + 8);
}

// ---------------------------------------------------------------------------
// MFMA QKV GEMM, split-bf16 — m97 structure (single-buffered 32KB LDS, two
// barriers/K-step, 3 blocks/CU) + VECTORIZED epilogue via per-wave LDS bounce
// (64 scalar stores/thread -> 16 float4 stores/thread; pe/wmap float4 loads).
// ---------------------------------------------------------------------------
__global__ __launch_bounds__(256, 3) void gemm_qkv_mfma(
    const u16* __restrict__ whi, const u16* __restrict__ wlo,
    const u16* __restrict__ b1hi, const u16* __restrict__ b1lo,
    const u16* __restrict__ b2hi, const u16* __restrict__ b2lo,
    const float* __restrict__ qb, const float* __restrict__ kbias,
    const float* __restrict__ vb, const float* __restrict__ wvis,
    const float* __restrict__ wir, const float* __restrict__ Ttab,
    float* __restrict__ qo, float* __restrict__ ko, float* __restrict__ vo)
{
    __shared__ u16 AH[4096], AL[4096], BH[4096], BL[4096];   // 32KB staging
    __shared__ float SB[4][16][68];                          // 17KB epilogue

    int t = threadIdx.x;
    // bijective XCD-chunk swizzle: 432 = 54*8; consecutive roles share an XCD
    int d = blockIdx.x + 6 * blockIdx.y;           // 0..431 (dispatch order)
    int role = (d & 7) * 54 + (d >> 3);
    int mat = role / 144, rem = role - mat * 144;
    int bn = rem >> 1, mtile = rem & 1;            // mtile pair adjacent roles
    int b = blockIdx.z;

    const u16* gBh = ((mat == 0) ? b1hi : b2hi) + (size_t)b * PERB + (size_t)bn * 32768;
    const u16* gBl = ((mat == 0) ? b1lo : b2lo) + (size_t)b * PERB + (size_t)bn * 32768;
    const u16* gAh = whi + (size_t)(mat * 2 + mtile) * 32768;
    const u16* gAl = wlo + (size_t)(mat * 2 + mtile) * 32768;
    int wv = t >> 6;
    int wm = t >> 7, wn = (t >> 6) & 1;
    int rr = t & 15, gq = (t >> 4) & 3;

    // f-independent swizzled frag base offsets (u16 units); frag f adds f*512
    int sxor = (gq ^ ((rr >> 1) & 3)) * 8;
    int offA0 = (wm * 64 + rr) * 32 + sxor;
    int offB0 = (wn * 64 + rr) * 32 + sxor;

    f32x4 acc[4][4];
#pragma unroll
    for (int i = 0; i < 4; ++i)
#pragma unroll
        for (int j = 0; j < 4; ++j) acc[i][j] = (f32x4){0.f, 0.f, 0.f, 0.f};

    for (int kq = 0; kq < 8; ++kq) {
        {   // stage A+B tile (32KB, 8 x glds16 per thread, linear dest)
            const u16* sah = gAh + kq * 4096 + t * 8;
            const u16* sal = gAl + kq * 4096 + t * 8;
            const u16* sbh = gBh + kq * 4096 + t * 8;
            const u16* sbl = gBl + kq * 4096 + t * 8;
            glds16(sah,        &AH[t * 8]);
            glds16(sah + 2048, &AH[t * 8 + 2048]);
            glds16(sal,        &AL[t * 8]);
            glds16(sal + 2048, &AL[t * 8 + 2048]);
            glds16(sbh,        &BH[t * 8]);
            glds16(sbh + 2048, &BH[t * 8 + 2048]);
            glds16(sbl,        &BL[t * 8]);
            glds16(sbl + 2048, &BL[t * 8 + 2048]);
        }
        __syncthreads();       // compiler drains vmcnt here (m97 structure)

        short8 bh[4], bl[4];
#pragma unroll
        for (int r = 0; r < 4; ++r) {
            bh[r] = *(const short8*)(&BH[offB0 + r * 512]);
            bl[r] = *(const short8*)(&BL[offB0 + r * 512]);
        }
#pragma unroll
        for (int f = 0; f < 4; ++f) {
            short8 ah = *(const short8*)(&AH[offA0 + f * 512]);
            short8 al = *(const short8*)(&AL[offA0 + f * 512]);
#pragma unroll
            for (int r = 0; r < 4; ++r) {
                acc[f][r] = __builtin_amdgcn_mfma_f32_16x16x32_bf16(ah, bh[r], acc[f][r], 0, 0, 0);
                acc[f][r] = __builtin_amdgcn_mfma_f32_16x16x32_bf16(ah, bl[r], acc[f][r], 0, 0, 0);
                acc[f][r] = __builtin_amdgcn_mfma_f32_16x16x32_bf16(al, bh[r], acc[f][r], 0, 0, 0);
            }
        }
        __syncthreads();       // protect LDS overwrite by next K-step
    }

    // ---- vectorized epilogue: per-wave LDS bounce, float4 stores ----
    const float* wmap = ((mat == 0) ? wvis : wir) + (size_t)b * NPOS;
    const float* bias = (mat == 0) ? qb : (mat == 1) ? kbias : vb;
    float* outp = ((mat == 0) ? qo : (mat == 1) ? ko : vo) + (size_t)b * PERB;
    bool addpe = (mat != 2);

    int lane = t & 63;
    int lrow = lane >> 2;           // 0..15 (o-row within 16-slab)
    int lq   = lane & 3;            // col quarter
    int base_n = bn * 128 + wn * 64;

#pragma unroll
    for (int f = 0; f < 4; ++f) {
        // scatter this wave's 16x64 acc slab into SB (2-way banks = free)
#pragma unroll
        for (int r = 0; r < 4; ++r)
#pragma unroll
            for (int ri = 0; ri < 4; ++ri)
                SB[wv][gq * 4 + ri][r * 16 + rr] = acc[f][r][ri];
        // gather rows: lane owns (o = base_o + lrow, n = base_n + lq*16 + 4q)
        int o = mtile * 128 + wm * 64 + f * 16 + lrow;
        float bo = bias[o];
        const float* tro = Ttab + o * 96;
        float* orow = outp + (size_t)o * NPOS;
#pragma unroll
        for (int qd = 0; qd < 4; ++qd) {
            int c0 = lq * 16 + qd * 4;
            int n = base_n + c0;
            float4 v4 = *(float4*)&SB[wv][lrow][c0];
            float4 s4 = *(const float4*)&wmap[n];
            float4 o4;
            if (addpe) {
                int hh = n / 96, ww = n - hh * 96;   // quad never crosses a row
                float4 pw4 = *(const float4*)&tro[ww];
                float ph = tro[hh];
                o4.x = v4.x * s4.x + bo + pw4.x + ph;
                o4.y = v4.y * s4.y + bo + pw4.y + ph;
                o4.z = v4.z * s4.z + bo + pw4.z + ph;
                o4.w = v4.w * s4.w + bo + pw4.w + ph;
            } else {
                o4.x = v4.x * s4.x + bo;
                o4.y = v4.y * s4.y + bo;
                o4.z = v4.z * s4.z + bo;
                o4.w = v4.w * s4.w + bo;
            }
            *(float4*)&orow[n] = o4;
        }
        // next f reuses SB; wave-internal LDS ordering handles the hazard
    }
}

// ---------------------------------------------------------------------------
// Attention per (b,c): 2-buffer LDS (77KB -> 2 blocks/CU).
// R1 = q then attn; R2 = k then v.  Contiguous f32 output (coalesced).
// ---------------------------------------------------------------------------
__global__ __launch_bounds__(256) void attn_kernel(
    const float* __restrict__ q, const float* __restrict__ k,
    const float* __restrict__ v, float* __restrict__ fused)
{
    __shared__ float R1[96 * 100];  // q, later attn
    __shared__ float R2[96 * 100];  // k, later v

    int t  = threadIdx.x;
    int bc = blockIdx.x;
    const size_t base = (size_t)bc * NPOS;

    for (int f = t; f < 96 * 24; f += 256) {
        int r = f / 24, w4 = (f % 24) * 4;
        *(float4*)(R1 + r * 100 + w4) = *(const float4*)(q + base + r * 96 + w4);
        *(float4*)(R2 + r * 100 + w4) = *(const float4*)(k + base + r * 96 + w4);
    }
    __syncthreads();

    int tx = t & 15, ty = t >> 4;
    int h0 = ty * 6, g0 = tx * 6;

    float acc[6][6];
#pragma unroll
    for (int i = 0; i < 6; ++i)
#pragma unroll
        for (int j = 0; j < 6; ++j) acc[i][j] = 0.0f;

    for (int w4 = 0; w4 < 24; ++w4) {
        float4 qv[6], kv[6];
#pragma unroll
        for (int i = 0; i < 6; ++i) qv[i] = *(const float4*)(R1 + (h0 + i) * 100 + w4 * 4);
#pragma unroll
        for (int j = 0; j < 6; ++j) kv[j] = *(const float4*)(R2 + (g0 + j) * 100 + w4 * 4);
#pragma unroll
        for (int i = 0; i < 6; ++i)
#pragma unroll
            for (int j = 0; j < 6; ++j) {
                acc[i][j] = fmaf(qv[i].x, kv[j].x, acc[i][j]);
                acc[i][j] = fmaf(qv[i].y, kv[j].y, acc[i][j]);
                acc[i][j] = fmaf(qv[i].z, kv[j].z, acc[i][j]);
                acc[i][j] = fmaf(qv[i].w, kv[j].w, acc[i][j]);
            }
    }

#pragma unroll
    for (int i = 0; i < 6; ++i) {
        float m = acc[i][0];
#pragma unroll
        for (int j = 1; j < 6; ++j) m = fmaxf(m, acc[i][j]);
        for (int d = 1; d < 16; d <<= 1) m = fmaxf(m, __shfl_xor(m, d));
        float s = 0.0f;
#pragma unroll
        for (int j = 0; j < 6; ++j) {
            acc[i][j] = __expf(acc[i][j] - m);
            s += acc[i][j];
        }
        for (int d = 1; d < 16; d <<= 1) s += __shfl_xor(s, d);
        float inv = 1.0f / s;
#pragma unroll
        for (int j = 0; j < 6; ++j) acc[i][j] *= inv;
    }

    __syncthreads();
#pragma unroll
    for (int i = 0; i < 6; ++i)
#pragma unroll
        for (int j = 0; j < 6; ++j) R1[(h0 + i) * 100 + g0 + j] = acc[i][j];
    for (int f = t; f < 96 * 24; f += 256) {
        int r = f / 24, w4 = (f % 24) * 4;
        *(float4*)(R2 + r * 100 + w4) = *(const float4*)(v + base + r * 96 + w4);
    }
    __syncthreads();

    int w0 = tx * 6;
    float outv[6][6];
#pragma unroll
    for (int i = 0; i < 6; ++i)
#pragma unroll
        for (int j = 0; j < 6; ++j) outv[i][j] = 0.0f;

    for (int g4 = 0; g4 < 24; ++g4) {
        float4 av[6];
#pragma unroll
        for (int i = 0; i < 6; ++i) av[i] = *(const float4*)(R1 + (h0 + i) * 100 + g4 * 4);
#pragma unroll
        for (int gg = 0; gg < 4; ++gg) {
            int g = g4 * 4 + gg;
            float vr[6];
#pragma unroll
            for (int j = 0; j < 6; ++j) vr[j] = R2[g * 100 + w0 + j];
#pragma unroll
            for (int i = 0; i < 6; ++i) {
                float a = (gg == 0) ? av[i].x : (gg == 1) ? av[i].y : (gg == 2) ? av[i].z : av[i].w;
#pragma unroll
                for (int j = 0; j < 6; ++j) outv[i][j] = fmaf(a, vr[j], outv[i][j]);
            }
        }
    }

#pragma unroll
    for (int i = 0; i < 6; ++i) {
        float* op = fused + base + (size_t)(h0 + i) * 96 + w0;
#pragma unroll
        for (int j = 0; j < 6; ++j) op[j] = outv[i][j];
    }
}

// ---------------------------------------------------------------------------
// Final projection: out[b][o][n] = sum_c proj_w[o][c]*fused[b][c][n] + pb[o]
// ---------------------------------------------------------------------------
__global__ __launch_bounds__(256) void proj_kernel(
    const float* __restrict__ fused, const float* __restrict__ pw,
    const float* __restrict__ pb, float* __restrict__ out)
{
    __shared__ float As[16 * 68];
    __shared__ float Bs[16 * 128];

    int t  = threadIdx.x;
    int n0 = blockIdx.x * 128;
    int b  = blockIdx.y;
    const float* B = fused + (size_t)b * PERB;
    int tx = t & 15, ty = t >> 4;

    float acc[4][8];
#pragma unroll
    for (int i = 0; i < 4; ++i)
#pragma unroll
        for (int j = 0; j < 8; ++j) acc[i][j] = 0.0f;

    for (int k0 = 0; k0 < 256; k0 += 16) {
        {
            int m = t >> 2, c4 = (t & 3) * 4;
            float4 av = *(const float4*)(pw + (size_t)m * 256 + k0 + c4);
            As[(c4 + 0) * 68 + m] = av.x;
            As[(c4 + 1) * 68 + m] = av.y;
            As[(c4 + 2) * 68 + m] = av.z;
            As[(c4 + 3) * 68 + m] = av.w;
        }
#pragma unroll
        for (int l = 0; l < 2; ++l) {
            int f = t + l * 256;
            int c = f >> 5, n4 = (f & 31) * 4;
            *(float4*)(Bs + c * 128 + n4) =
                *(const float4*)(B + (size_t)(k0 + c) * NPOS + n0 + n4);
        }
        __syncthreads();
#pragma unroll
        for (int kk = 0; kk < 16; ++kk) {
            float a[4], bb[8];
            *(float4*)(&a[0])  = *(const float4*)(As + kk * 68 + ty * 4);
            *(float4*)(&bb[0]) = *(const float4*)(Bs + kk * 128 + tx * 8);
            *(float4*)(&bb[4]) = *(const float4*)(Bs + kk * 128 + tx * 8 + 4);
#pragma unroll
            for (int i = 0; i < 4; ++i)
#pragma unroll
                for (int j = 0; j < 8; ++j)
                    acc[i][j] = fmaf(a[i], bb[j], acc[i][j]);
        }
        __syncthreads();
    }

    int n = n0 + tx * 8;
#pragma unroll
    for (int i = 0; i < 4; ++i) {
        int o = ty * 4 + i;
        float bias = pb[o];
        float vals[8];
#pragma unroll
        for (int j = 0; j < 8; ++j) vals[j] = acc[i][j] + bias;
        float* op = out + ((size_t)b * 64 + o) * NPOS + n;
        *(float4*)(op)     = *(float4*)(&vals[0]);
        *(float4*)(op + 4) = *(float4*)(&vals[4]);
    }
}

// ---------------------------------------------------------------------------
extern "C" void kernel_launch(void* const* d_in, const int* in_sizes, int n_in,
                              void* d_out, int out_size, void* d_ws, size_t ws_size,
                              hipStream_t stream)
{
    const float* x1   = (const float*)d_in[0];
    const float* x2   = (const float*)d_in[1];
    const float* wvis = (const float*)d_in[2];
    const float* wir  = (const float*)d_in[3];
    const float* qw   = (const float*)d_in[4];
    const float* qb   = (const float*)d_in[5];
    const float* kw   = (const float*)d_in[6];
    const float* kb   = (const float*)d_in[7];
    const float* vw   = (const float*)d_in[8];
    const float* vb   = (const float*)d_in[9];
    const float* pw   = (const float*)d_in[10];
    const float* pb   = (const float*)d_in[11];
    float* out = (float*)d_out;

    float* ws = (float*)d_ws;
    size_t F = ws_size / 4;
    size_t fixed = 700000;   // T table (24576) + weights (~590K f32-equiv)
    size_t avail = (F > fixed) ? (F - fixed) : 0;
    int G = (int)(avail / (6 * PERB));
    if (G < 1) G = 1;
    if (G > 8) G = 8;

    float* ttab  = ws;                       // 24576 floats
    float* qbuf  = ws + 24576;
    float* kbuf  = qbuf + (size_t)G * PERB;
    float* vbuf  = kbuf + (size_t)G * PERB;
    float* fbuf  = vbuf + (size_t)G * PERB;
    u16*   b1hi  = (u16*)(fbuf + (size_t)G * PERB);
    u16*   b1lo  = b1hi + (size_t)G * PERB;
    u16*   b2hi  = b1lo + (size_t)G * PERB;
    u16*   b2lo  = b2hi + (size_t)G * PERB;
    u16*   whiP  = b2lo + (size_t)G * PERB;
    u16*   wloP  = whiP + 589824;

    tt_kernel<<<dim3(96), 256, 0, stream>>>(ttab);
    wsplit<<<dim3(144), 256, 0, stream>>>(qw, kw, vw, whiP, wloP);

    for (int b0 = 0; b0 < 16; b0 += G) {
        int g = (16 - b0 < G) ? (16 - b0) : G;
        splitcvt<<<dim3(576, g), 256, 0, stream>>>(x1 + (size_t)b0 * PERB, b1hi, b1lo);
        splitcvt<<<dim3(576, g), 256, 0, stream>>>(x2 + (size_t)b0 * PERB, b2hi, b2lo);
        for (int s = 0; s < 3; ++s) {
            if (s > 0)
                splitcvt<<<dim3(576, g), 256, 0, stream>>>(fbuf, b1hi, b1lo);
            const u16* xh = (s == 0) ? b2hi : b1hi;
            const u16* xl = (s == 0) ? b2lo : b1lo;
            gemm_qkv_mfma<<<dim3(6, 72, g), 256, 0, stream>>>(
                whiP + (size_t)s * 196608, wloP + (size_t)s * 196608,
                b1hi, b1lo, xh, xl,
                qb + (size_t)s * 256, kb + (size_t)s * 256, vb + (size_t)s * 256,
                wvis + (size_t)b0 * NPOS, wir + (size_t)b0 * NPOS,
                ttab, qbuf, kbuf, vbuf);
            attn_kernel<<<dim3(256 * g), 256, 0, stream>>>(qbuf, kbuf, vbuf, fbuf);
        }
        proj_kernel<<<dim3(72, g), 256, 0, stream>>>(
            fbuf, pw, pb, out + (size_t)b0 * 64 * NPOS);
    }
}